// Round 11
// baseline (765.192 us; speedup 1.0000x reference)
//
#include <hip/hip_runtime.h>

#define NGRAPH 16384
#define NPG    9
#define DM     128
#define NLAY   4
#define EPG    16
#define GPB    14
#define RPB    128
#define NBLK   1171   /* ceil(16384/14) */
#define CBS    40     /* Cb padded stride (elems) */
#define WPL    147456 /* weight elems per layer in wsT */

typedef __attribute__((ext_vector_type(8))) short bf16x8;
typedef __attribute__((ext_vector_type(4))) float f32x4;

__device__ __forceinline__ float b2f(unsigned short u){
  union { unsigned int i; float f; } v; v.i = ((unsigned int)u) << 16; return v.f;
}
__device__ __forceinline__ unsigned short f2b(float f){
  union { float fv; unsigned int i; } v; v.fv = f;
  unsigned int r = v.i + 0x7FFFu + ((v.i >> 16) & 1u);
  return (unsigned short)(r >> 16);
}

__device__ __forceinline__ bf16x8 ldfrag128(const unsigned short* buf, int row, int kk, int g16){
  return *(const bf16x8*)&buf[row*DM + ((kk*32 + g16*8) ^ ((row & 7) << 3))];
}
__device__ __forceinline__ f32x4 mfma16(bf16x8 a, bf16x8 b, f32x4 c){
  return __builtin_amdgcn_mfma_f32_16x16x32_bf16(a, b, c, 0, 0, 0);
}

// Weight pre-transform: f32 -> bf16, fragment-linear in wsT.
// Per layer l (base l*WPL), frag slot s of 288, each 512 bf16 (64 lanes x 8):
//  s 0..31   : GCN Wg   frag (kk=s>>3, nt=s&7)           k=kk*32+g16*8+e, n=nt*16+l15
//  s 32..159 : W1 chunk c=(s-32)>>3, fi=(s-32)&7 -> kk=fi>>1, nt=fi&1;
//              k=kk*32+g16*8+e, n=c*32+nt*16+l15
//  s 160..287: W2 chunk c=(s-160)>>3, nt=(s-160)&7; k=c*32+g16*8+e, n=nt*16+l15
__global__ void wtr_kernel(const float* __restrict__ Wg,
                           const float* __restrict__ W1,
                           const float* __restrict__ W2,
                           unsigned short* __restrict__ wsT){
  int idx = blockIdx.x * 256 + threadIdx.x;   // 2304 blocks -> 589824 = 1152*512
  int e    = idx & 7;
  int lane = (idx >> 3) & 63;
  int f    = idx >> 9;                        // 0..1151
  int l = f / 288, s = f - l*288;
  int l15 = lane & 15, g16 = lane >> 4;
  float v;
  if (s < 32){
    int kk = s >> 3, nt = s & 7;
    v = Wg[l*16384 + (kk*32 + g16*8 + e)*128 + nt*16 + l15];
  } else if (s < 160){
    int s2 = s - 32; int c = s2 >> 3, fi = s2 & 7;
    int kk = fi >> 1, nt = fi & 1;
    v = W1[l*65536 + (kk*32 + g16*8 + e)*512 + c*32 + nt*16 + l15];
  } else {
    int s3 = s - 160; int c = s3 >> 3, nt = s3 & 7;
    v = W2[l*65536 + (c*32 + g16*8 + e)*128 + nt*16 + l15];
  }
  wsT[f*512 + lane*8 + e] = f2b(v);
}

__global__ void __launch_bounds__(256, 3)
gcn_kernel(const float* __restrict__ op_table,
           const float* __restrict__ dev_emb,
           const float* __restrict__ bgp,
           const float* __restrict__ lngp,
           const float* __restrict__ lnbp,
           const float* __restrict__ b1p,
           const float* __restrict__ b2p,
           const float* __restrict__ fcw,
           const float* __restrict__ fcb,
           const int* __restrict__ op_idx,
           const int* __restrict__ srcA,
           const int* __restrict__ dstA,
           const unsigned short* __restrict__ wsT,
           float* __restrict__ out)
{
  __shared__ unsigned short H[RPB*DM];     // 32 KB: h / agg / X, swizzled stride-128
  __shared__ unsigned short Cb[RPB*CBS];   // 10 KB: Hc chunk (stride 40, wave-own rows)
  __shared__ float cntF[GPB][81];          // normalized adjacency (isd folded)
  __shared__ float isd_s[RPB];
  __shared__ float bg_s[DM], lng_s[DM], lnb_s[DM], b2_s[DM];
  __shared__ float b1_s[4*DM];

  const int tid  = threadIdx.x;
  const int w    = tid >> 6;
  const int lane = tid & 63;
  const int g16  = lane >> 4;
  const int l15  = lane & 15;
  const int rbase = w * 32;
  const int g0 = blockIdx.x * GPB;
  const int nvalid = (NGRAPH - g0 < GPB) ? (NGRAPH - g0) : GPB;

  // ---------------- preamble ----------------
  for (int i = tid; i < GPB*81; i += 256) (&cntF[0][0])[i] = 0.f;

  { // h0 = op_table[idx] + device_emb -> H swizzled; zeros for pad/invalid rows
    int r  = tid >> 1;
    int gh = (tid & 1) * 8;
    int gi = r / NPG;
    int j  = r - gi*NPG;
    if (r < GPB*NPG && gi < nvalid) {
      int idx = op_idx[(g0 + gi)*NPG + j];
      const float4* ot = (const float4*)&op_table[idx*DM + gh*8];
      const float4* de = (const float4*)&dev_emb[gh*8];
      #pragma unroll
      for (int i = 0; i < 8; ++i){
        float4 a0 = ot[2*i], a1 = ot[2*i+1];
        float4 d0 = de[2*i], d1 = de[2*i+1];
        bf16x8 o;
        o[0] = (short)f2b(a0.x + d0.x); o[1] = (short)f2b(a0.y + d0.y);
        o[2] = (short)f2b(a0.z + d0.z); o[3] = (short)f2b(a0.w + d0.w);
        o[4] = (short)f2b(a1.x + d1.x); o[5] = (short)f2b(a1.y + d1.y);
        o[6] = (short)f2b(a1.z + d1.z); o[7] = (short)f2b(a1.w + d1.w);
        int g = gh + i;
        *(bf16x8*)&H[r*DM + ((g ^ (r & 7)) << 3)] = o;
      }
    } else {
      bf16x8 z;
      #pragma unroll
      for (int q = 0; q < 8; ++q) z[q] = 0;
      #pragma unroll
      for (int i = 0; i < 8; ++i){
        int g = gh + i;
        *(bf16x8*)&H[r*DM + ((g ^ (r & 7)) << 3)] = z;
      }
    }
  }
  __syncthreads();

  if (tid < GPB && tid < nvalid) { // 9x9 count matrix incl. self loops
    float* c = cntF[tid];
    for (int e = 0; e < EPG; ++e){
      int s = srcA[(g0 + tid)*EPG + e];
      int d = dstA[(g0 + tid)*EPG + e];
      c[(s % NPG)*NPG + (d % NPG)] += 1.f;
    }
    #pragma unroll
    for (int j = 0; j < NPG; ++j) c[j*NPG + j] += 1.f;
  }
  __syncthreads();

  if (tid < RPB) { // isd = rsqrt(column sums)
    int gi = tid / NPG;
    if (tid < GPB*NPG && gi < nvalid) {
      int jd = tid - gi*NPG;
      float s = 0.f;
      #pragma unroll
      for (int js = 0; js < NPG; ++js) s += cntF[gi][js*NPG + jd];
      isd_s[tid] = rsqrtf(s);
    } else isd_s[tid] = 1.f;
  }
  __syncthreads();

  for (int idx = tid; idx < GPB*81; idx += 256){ // fold isd into cnt
    int gi = idx / 81;
    int e  = idx - gi*81;
    int js = e / 9, jd = e - js*9;
    (&cntF[0][0])[idx] *= isd_s[gi*NPG + js] * isd_s[gi*NPG + jd];
  }
  __syncthreads();

  #pragma unroll 1
  for (int l = 0; l < NLAY; ++l){
    const unsigned short* WL = wsT + l*WPL;

    // ---------- Phase A: biases + in-place agg on H (cross-wave) ----------
    if (tid < DM) {
      bg_s[tid]  = bgp [l*DM + tid];
      lng_s[tid] = lngp[l*DM + tid];
      lnb_s[tid] = lnbp[l*DM + tid];
      b2_s[tid]  = b2p [l*DM + tid];
    }
    b1_s[tid]       = b1p[l*4*DM + tid];
    b1_s[tid + 256] = b1p[l*4*DM + 256 + tid];
    {
      int gi = tid >> 4;
      int g  = tid & 15;
      if (gi < GPB) {
        float hs[NPG][8];
        #pragma unroll
        for (int j = 0; j < NPG; ++j){
          int row = gi*NPG + j;
          bf16x8 hv = *(const bf16x8*)&H[row*DM + ((g ^ (row & 7)) << 3)];
          #pragma unroll
          for (int i = 0; i < 8; ++i) hs[j][i] = b2f((unsigned short)hv[i]);
        }
        #pragma unroll
        for (int jd = 0; jd < NPG; ++jd){
          float av[8];
          #pragma unroll
          for (int i = 0; i < 8; ++i) av[i] = 0.f;
          #pragma unroll
          for (int js = 0; js < NPG; ++js){
            float cc = cntF[gi][js*NPG + jd];
            #pragma unroll
            for (int i = 0; i < 8; ++i) av[i] = fmaf(cc, hs[js][i], av[i]);
          }
          int row = gi*NPG + jd;
          bf16x8 o;
          #pragma unroll
          for (int i = 0; i < 8; ++i) o[i] = (short)f2b(av[i]);
          *(bf16x8*)&H[row*DM + ((g ^ (row & 7)) << 3)] = o;
        }
      } else { // zero pad rows 126,127
        int k2 = tid - GPB*16;
        int row = GPB*NPG + (k2 >> 4);
        int gg = k2 & 15;
        bf16x8 z;
        #pragma unroll
        for (int q = 0; q < 8; ++q) z[q] = 0;
        *(bf16x8*)&H[row*DM + ((gg ^ (row & 7)) << 3)] = z;
      }
    }
    __syncthreads();   // barrier 1: agg + biases visible

    // ---------- GCN GEMM (B from global) + ReLU + LN -> X in H (wave-local) ----------
    {
      const bf16x8* Bf = (const bf16x8*)WL;
      f32x4 acc[2][8];
      #pragma unroll
      for (int mt = 0; mt < 2; ++mt)
        #pragma unroll
        for (int nt = 0; nt < 8; ++nt){ f32x4 z; z[0]=z[1]=z[2]=z[3]=0.f; acc[mt][nt]=z; }
      #pragma unroll 1
      for (int kk = 0; kk < 4; ++kk){
        bf16x8 a0 = ldfrag128(H, rbase + l15, kk, g16);
        bf16x8 a1 = ldfrag128(H, rbase + 16 + l15, kk, g16);
        __builtin_amdgcn_s_setprio(1);
        #pragma unroll
        for (int nt = 0; nt < 8; ++nt){
          bf16x8 bb = Bf[(kk*8 + nt)*64 + lane];
          acc[0][nt] = mfma16(a0, bb, acc[0][nt]);
          acc[1][nt] = mfma16(a1, bb, acc[1][nt]);
        }
        __builtin_amdgcn_s_setprio(0);
      }
      #pragma unroll
      for (int mt = 0; mt < 2; ++mt){
        float rs[4], rq[4];
        #pragma unroll
        for (int j = 0; j < 4; ++j){ rs[j] = 0.f; rq[j] = 0.f; }
        #pragma unroll
        for (int nt = 0; nt < 8; ++nt){
          #pragma unroll
          for (int j = 0; j < 4; ++j){
            float v = acc[mt][nt][j] + bg_s[nt*16 + l15];
            v = fmaxf(v, 0.f);
            acc[mt][nt][j] = v;
            rs[j] += v; rq[j] += v*v;
          }
        }
        #pragma unroll
        for (int j = 0; j < 4; ++j){
          #pragma unroll
          for (int mm = 1; mm < 16; mm <<= 1){
            rs[j] += __shfl_xor(rs[j], mm, 64);
            rq[j] += __shfl_xor(rq[j], mm, 64);
          }
          float mu  = rs[j] * (1.f/128.f);
          float var = rq[j] * (1.f/128.f) - mu*mu;
          rs[j] = mu;
          rq[j] = rsqrtf(var + 1e-5f);
        }
        int rowb = rbase + mt*16 + g16*4;
        #pragma unroll
        for (int nt = 0; nt < 8; ++nt){
          int col = nt*16 + l15;
          float lg = lng_s[col], lb = lnb_s[col];
          #pragma unroll
          for (int j = 0; j < 4; ++j){
            float x = (acc[mt][nt][j] - rs[j]) * rq[j] * lg + lb;
            int row = rowb + j;
            H[row*DM + (col ^ ((row & 7) << 3))] = f2b(x);
          }
        }
      }
    }

    // ---------- FFN: 16 chunks of 32 hidden, all wave-local, no barriers ----------
    {
      const unsigned short* W1b = WL + 16384;
      const unsigned short* W2b = WL + 81920;
      f32x4 c2[2][8];
      #pragma unroll
      for (int mt = 0; mt < 2; ++mt)
        #pragma unroll
        for (int nt = 0; nt < 8; ++nt){ f32x4 z; z[0]=z[1]=z[2]=z[3]=0.f; c2[mt][nt]=z; }
      #pragma unroll 1
      for (int c = 0; c < 16; ++c){
        // FFN1: Hc = relu(X @ W1c + b1c) -> Cb (stride 40, own rows)
        const bf16x8* B1 = (const bf16x8*)(W1b + c*4096);
        f32x4 hc[2][2];
        #pragma unroll
        for (int mt = 0; mt < 2; ++mt)
          #pragma unroll
          for (int nt = 0; nt < 2; ++nt){ f32x4 z; z[0]=z[1]=z[2]=z[3]=0.f; hc[mt][nt]=z; }
        #pragma unroll 1
        for (int kk = 0; kk < 4; ++kk){
          bf16x8 a0 = ldfrag128(H, rbase + l15, kk, g16);
          bf16x8 a1 = ldfrag128(H, rbase + 16 + l15, kk, g16);
          __builtin_amdgcn_s_setprio(1);
          #pragma unroll
          for (int nt = 0; nt < 2; ++nt){
            bf16x8 bb = B1[(kk*2 + nt)*64 + lane];
            hc[0][nt] = mfma16(a0, bb, hc[0][nt]);
            hc[1][nt] = mfma16(a1, bb, hc[1][nt]);
          }
          __builtin_amdgcn_s_setprio(0);
        }
        #pragma unroll
        for (int mt = 0; mt < 2; ++mt){
          int rowb = rbase + mt*16 + g16*4;
          #pragma unroll
          for (int nt = 0; nt < 2; ++nt){
            int col = nt*16 + l15;
            float bv = b1_s[c*32 + col];
            #pragma unroll
            for (int j = 0; j < 4; ++j){
              float v = fmaxf(hc[mt][nt][j] + bv, 0.f);
              Cb[(rowb + j)*CBS + col] = f2b(v);
            }
          }
        }
        // FFN2: c2 += Hc @ W2c (K=32; same-wave LDS dep via lgkmcnt)
        const bf16x8* B2 = (const bf16x8*)(W2b + c*4096);
        {
          bf16x8 a0 = *(const bf16x8*)&Cb[(rbase + l15)*CBS + g16*8];
          bf16x8 a1 = *(const bf16x8*)&Cb[(rbase + 16 + l15)*CBS + g16*8];
          __builtin_amdgcn_s_setprio(1);
          #pragma unroll
          for (int nt = 0; nt < 8; ++nt){
            bf16x8 bb = B2[nt*64 + lane];
            c2[0][nt] = mfma16(a0, bb, c2[0][nt]);
            c2[1][nt] = mfma16(a1, bb, c2[1][nt]);
          }
          __builtin_amdgcn_s_setprio(0);
        }
      }

      // ---------- Phase D: h = X + c2 + b2 -> H (in place, own rows) ----------
      #pragma unroll
      for (int mt = 0; mt < 2; ++mt){
        int rowb = rbase + mt*16 + g16*4;
        #pragma unroll
        for (int nt = 0; nt < 8; ++nt){
          int col = nt*16 + l15;
          float b2v = b2_s[col];
          #pragma unroll
          for (int j = 0; j < 4; ++j){
            int row = rowb + j;
            int p = row*DM + (col ^ ((row & 7) << 3));
            float x = b2f(H[p]);
            H[p] = f2b(x + c2[mt][nt][j] + b2v);
          }
        }
      }
    }
    __syncthreads();   // barrier 2: h visible for next layer / readout
  }

  // ---------------- readout ----------------
  {
    int gi = tid >> 4;
    int g  = tid & 15;
    if (gi < nvalid) {
      float m[8];
      #pragma unroll
      for (int i = 0; i < 8; ++i) m[i] = 0.f;
      #pragma unroll
      for (int j = 0; j < NPG; ++j){
        int row = gi*NPG + j;
        bf16x8 hv = *(const bf16x8*)&H[row*DM + ((g ^ (row & 7)) << 3)];
        #pragma unroll
        for (int i = 0; i < 8; ++i) m[i] += b2f((unsigned short)hv[i]);
      }
      const float4* fw = (const float4*)&fcw[g*8];
      float4 w0 = fw[0], w1 = fw[1];
      float dot = m[0]*w0.x + m[1]*w0.y + m[2]*w0.z + m[3]*w0.w
                + m[4]*w1.x + m[5]*w1.y + m[6]*w1.z + m[7]*w1.w;
      dot *= (1.f/9.f);
      #pragma unroll
      for (int mm = 1; mm < 16; mm <<= 1) dot += __shfl_xor(dot, mm, 64);
      if ((tid & 15) == 0){
        float z = dot + fcb[0];
        out[g0 + gi] = 1.f / (1.f + __expf(-z));
      }
    }
  }
}

extern "C" void kernel_launch(void* const* d_in, const int* in_sizes, int n_in,
                              void* d_out, int out_size, void* d_ws, size_t ws_size,
                              hipStream_t stream)
{
  const float* op_table = (const float*)d_in[0];
  const float* dev_emb  = (const float*)d_in[1];
  const float* Wg  = (const float*)d_in[2];
  const float* bg  = (const float*)d_in[3];
  const float* lng = (const float*)d_in[4];
  const float* lnb = (const float*)d_in[5];
  const float* W1  = (const float*)d_in[6];
  const float* b1  = (const float*)d_in[7];
  const float* W2  = (const float*)d_in[8];
  const float* b2  = (const float*)d_in[9];
  const float* fcw = (const float*)d_in[10];
  const float* fcb = (const float*)d_in[11];
  const int* op_idx = (const int*)d_in[12];
  const int* srcA   = (const int*)d_in[13];
  const int* dstA   = (const int*)d_in[14];
  unsigned short* wsT = (unsigned short*)d_ws;

  wtr_kernel<<<2304, 256, 0, stream>>>(Wg, W1, W2, wsT);
  gcn_kernel<<<NBLK, 256, 0, stream>>>(op_table, dev_emb, bg, lng, lnb, b1, b2,
                                       fcw, fcb, op_idx, srcA, dstA, wsT,
                                       (float*)d_out);
}

// Round 12
// 458.153 us; speedup vs baseline: 1.6702x; 1.6702x over previous
//
#include <hip/hip_runtime.h>

#define NGRAPH 16384
#define NPG    9
#define DM     128
#define NLAY   4
#define EPG    16
#define GPB    14
#define RPB    128
#define NBLK   1171   /* ceil(16384/14) */
#define CBS    40     /* Cb padded stride (elems) */
#define WPL    147456 /* weight elems per layer in wsT */

typedef __attribute__((ext_vector_type(8))) short bf16x8;
typedef __attribute__((ext_vector_type(4))) float f32x4;

__device__ __forceinline__ float b2f(unsigned short u){
  union { unsigned int i; float f; } v; v.i = ((unsigned int)u) << 16; return v.f;
}
__device__ __forceinline__ unsigned short f2b(float f){
  union { float fv; unsigned int i; } v; v.fv = f;
  unsigned int r = v.i + 0x7FFFu + ((v.i >> 16) & 1u);
  return (unsigned short)(r >> 16);
}

__device__ __forceinline__ bf16x8 ldfrag128(const unsigned short* buf, int row, int kk, int g16){
  return *(const bf16x8*)&buf[row*DM + ((kk*32 + g16*8) ^ ((row & 7) << 3))];
}
__device__ __forceinline__ f32x4 mfma16(bf16x8 a, bf16x8 b, f32x4 c){
  return __builtin_amdgcn_mfma_f32_16x16x32_bf16(a, b, c, 0, 0, 0);
}

// Weight pre-transform: f32 -> bf16, fragment-linear in wsT.
// Per layer l (base l*WPL), frag slot s of 288, each 512 bf16 (64 lanes x 8):
//  s 0..31   : GCN Wg   frag (kk=s>>3, nt=s&7)           k=kk*32+g16*8+e, n=nt*16+l15
//  s 32..159 : W1 chunk c=(s-32)>>3, fi=(s-32)&7 -> kk=fi>>1, nt=fi&1;
//              k=kk*32+g16*8+e, n=c*32+nt*16+l15
//  s 160..287: W2 chunk c=(s-160)>>3, nt=(s-160)&7; k=c*32+g16*8+e, n=nt*16+l15
__global__ void wtr_kernel(const float* __restrict__ Wg,
                           const float* __restrict__ W1,
                           const float* __restrict__ W2,
                           unsigned short* __restrict__ wsT){
  int idx = blockIdx.x * 256 + threadIdx.x;   // 2304 blocks -> 589824 = 1152*512
  int e    = idx & 7;
  int lane = (idx >> 3) & 63;
  int f    = idx >> 9;                        // 0..1151
  int l = f / 288, s = f - l*288;
  int l15 = lane & 15, g16 = lane >> 4;
  float v;
  if (s < 32){
    int kk = s >> 3, nt = s & 7;
    v = Wg[l*16384 + (kk*32 + g16*8 + e)*128 + nt*16 + l15];
  } else if (s < 160){
    int s2 = s - 32; int c = s2 >> 3, fi = s2 & 7;
    int kk = fi >> 1, nt = fi & 1;
    v = W1[l*65536 + (kk*32 + g16*8 + e)*512 + c*32 + nt*16 + l15];
  } else {
    int s3 = s - 160; int c = s3 >> 3, nt = s3 & 7;
    v = W2[l*65536 + (c*32 + g16*8 + e)*128 + nt*16 + l15];
  }
  wsT[f*512 + lane*8 + e] = f2b(v);
}

__global__ void __launch_bounds__(256, 2)
gcn_kernel(const float* __restrict__ op_table,
           const float* __restrict__ dev_emb,
           const float* __restrict__ bgp,
           const float* __restrict__ lngp,
           const float* __restrict__ lnbp,
           const float* __restrict__ b1p,
           const float* __restrict__ b2p,
           const float* __restrict__ fcw,
           const float* __restrict__ fcb,
           const int* __restrict__ op_idx,
           const int* __restrict__ srcA,
           const int* __restrict__ dstA,
           const unsigned short* __restrict__ wsT,
           float* __restrict__ out)
{
  __shared__ unsigned short H[RPB*DM];     // 32 KB: h / agg / X, swizzled stride-128
  __shared__ unsigned short Cb[RPB*CBS];   // 10 KB: Hc chunk (stride 40, wave-own rows)
  __shared__ float cntF[GPB][81];          // normalized adjacency (isd folded)
  __shared__ float isd_s[RPB];
  __shared__ float bg_s[DM], lng_s[DM], lnb_s[DM], b2_s[DM];
  __shared__ float b1_s[4*DM];

  const int tid  = threadIdx.x;
  const int w    = tid >> 6;
  const int lane = tid & 63;
  const int g16  = lane >> 4;
  const int l15  = lane & 15;
  const int rbase = w * 32;
  const int g0 = blockIdx.x * GPB;
  const int nvalid = (NGRAPH - g0 < GPB) ? (NGRAPH - g0) : GPB;

  // ---------------- preamble ----------------
  for (int i = tid; i < GPB*81; i += 256) (&cntF[0][0])[i] = 0.f;

  { // h0 = op_table[idx] + device_emb -> H swizzled; zeros for pad/invalid rows
    int r  = tid >> 1;
    int gh = (tid & 1) * 8;
    int gi = r / NPG;
    int j  = r - gi*NPG;
    if (r < GPB*NPG && gi < nvalid) {
      int idx = op_idx[(g0 + gi)*NPG + j];
      const float4* ot = (const float4*)&op_table[idx*DM + gh*8];
      const float4* de = (const float4*)&dev_emb[gh*8];
      #pragma unroll
      for (int i = 0; i < 8; ++i){
        float4 a0 = ot[2*i], a1 = ot[2*i+1];
        float4 d0 = de[2*i], d1 = de[2*i+1];
        bf16x8 o;
        o[0] = (short)f2b(a0.x + d0.x); o[1] = (short)f2b(a0.y + d0.y);
        o[2] = (short)f2b(a0.z + d0.z); o[3] = (short)f2b(a0.w + d0.w);
        o[4] = (short)f2b(a1.x + d1.x); o[5] = (short)f2b(a1.y + d1.y);
        o[6] = (short)f2b(a1.z + d1.z); o[7] = (short)f2b(a1.w + d1.w);
        int g = gh + i;
        *(bf16x8*)&H[r*DM + ((g ^ (r & 7)) << 3)] = o;
      }
    } else {
      bf16x8 z;
      #pragma unroll
      for (int q = 0; q < 8; ++q) z[q] = 0;
      #pragma unroll
      for (int i = 0; i < 8; ++i){
        int g = gh + i;
        *(bf16x8*)&H[r*DM + ((g ^ (r & 7)) << 3)] = z;
      }
    }
  }
  __syncthreads();

  if (tid < GPB && tid < nvalid) { // 9x9 count matrix incl. self loops
    float* c = cntF[tid];
    for (int e = 0; e < EPG; ++e){
      int s = srcA[(g0 + tid)*EPG + e];
      int d = dstA[(g0 + tid)*EPG + e];
      c[(s % NPG)*NPG + (d % NPG)] += 1.f;
    }
    #pragma unroll
    for (int j = 0; j < NPG; ++j) c[j*NPG + j] += 1.f;
  }
  __syncthreads();

  if (tid < RPB) { // isd = rsqrt(column sums)
    int gi = tid / NPG;
    if (tid < GPB*NPG && gi < nvalid) {
      int jd = tid - gi*NPG;
      float s = 0.f;
      #pragma unroll
      for (int js = 0; js < NPG; ++js) s += cntF[gi][js*NPG + jd];
      isd_s[tid] = rsqrtf(s);
    } else isd_s[tid] = 1.f;
  }
  __syncthreads();

  for (int idx = tid; idx < GPB*81; idx += 256){ // fold isd into cnt
    int gi = idx / 81;
    int e  = idx - gi*81;
    int js = e / 9, jd = e - js*9;
    (&cntF[0][0])[idx] *= isd_s[gi*NPG + js] * isd_s[gi*NPG + jd];
  }
  __syncthreads();

  #pragma unroll 1
  for (int l = 0; l < NLAY; ++l){
    const unsigned short* WL = wsT + l*WPL;

    // ---------- Phase A: biases + in-place agg on H (cross-wave) ----------
    if (tid < DM) {
      bg_s[tid]  = bgp [l*DM + tid];
      lng_s[tid] = lngp[l*DM + tid];
      lnb_s[tid] = lnbp[l*DM + tid];
      b2_s[tid]  = b2p [l*DM + tid];
    }
    b1_s[tid]       = b1p[l*4*DM + tid];
    b1_s[tid + 256] = b1p[l*4*DM + 256 + tid];
    {
      int gi = tid >> 4;
      int g  = tid & 15;
      if (gi < GPB) {
        float hs[NPG][8];
        #pragma unroll
        for (int j = 0; j < NPG; ++j){
          int row = gi*NPG + j;
          bf16x8 hv = *(const bf16x8*)&H[row*DM + ((g ^ (row & 7)) << 3)];
          #pragma unroll
          for (int i = 0; i < 8; ++i) hs[j][i] = b2f((unsigned short)hv[i]);
        }
        #pragma unroll
        for (int jd = 0; jd < NPG; ++jd){
          float av[8];
          #pragma unroll
          for (int i = 0; i < 8; ++i) av[i] = 0.f;
          #pragma unroll
          for (int js = 0; js < NPG; ++js){
            float cc = cntF[gi][js*NPG + jd];
            #pragma unroll
            for (int i = 0; i < 8; ++i) av[i] = fmaf(cc, hs[js][i], av[i]);
          }
          int row = gi*NPG + jd;
          bf16x8 o;
          #pragma unroll
          for (int i = 0; i < 8; ++i) o[i] = (short)f2b(av[i]);
          *(bf16x8*)&H[row*DM + ((g ^ (row & 7)) << 3)] = o;
        }
      } else { // zero pad rows 126,127
        int k2 = tid - GPB*16;
        int row = GPB*NPG + (k2 >> 4);
        int gg = k2 & 15;
        bf16x8 z;
        #pragma unroll
        for (int q = 0; q < 8; ++q) z[q] = 0;
        *(bf16x8*)&H[row*DM + ((gg ^ (row & 7)) << 3)] = z;
      }
    }
    __syncthreads();   // barrier 1: agg + biases visible

    // ---------- GCN GEMM (B from global) + ReLU + LN -> X in H (wave-local) ----------
    {
      const bf16x8* Bf = (const bf16x8*)WL;
      f32x4 acc[2][8];
      #pragma unroll
      for (int mt = 0; mt < 2; ++mt)
        #pragma unroll
        for (int nt = 0; nt < 8; ++nt){ f32x4 z; z[0]=z[1]=z[2]=z[3]=0.f; acc[mt][nt]=z; }
      #pragma unroll 1
      for (int kk = 0; kk < 4; ++kk){
        bf16x8 a0 = ldfrag128(H, rbase + l15, kk, g16);
        bf16x8 a1 = ldfrag128(H, rbase + 16 + l15, kk, g16);
        __builtin_amdgcn_s_setprio(1);
        #pragma unroll
        for (int nt = 0; nt < 8; ++nt){
          bf16x8 bb = Bf[(kk*8 + nt)*64 + lane];
          acc[0][nt] = mfma16(a0, bb, acc[0][nt]);
          acc[1][nt] = mfma16(a1, bb, acc[1][nt]);
        }
        __builtin_amdgcn_s_setprio(0);
      }
      #pragma unroll
      for (int mt = 0; mt < 2; ++mt){
        float rs[4], rq[4];
        #pragma unroll
        for (int j = 0; j < 4; ++j){ rs[j] = 0.f; rq[j] = 0.f; }
        #pragma unroll
        for (int nt = 0; nt < 8; ++nt){
          #pragma unroll
          for (int j = 0; j < 4; ++j){
            float v = acc[mt][nt][j] + bg_s[nt*16 + l15];
            v = fmaxf(v, 0.f);
            acc[mt][nt][j] = v;
            rs[j] += v; rq[j] += v*v;
          }
        }
        #pragma unroll
        for (int j = 0; j < 4; ++j){
          #pragma unroll
          for (int mm = 1; mm < 16; mm <<= 1){
            rs[j] += __shfl_xor(rs[j], mm, 64);
            rq[j] += __shfl_xor(rq[j], mm, 64);
          }
          float mu  = rs[j] * (1.f/128.f);
          float var = rq[j] * (1.f/128.f) - mu*mu;
          rs[j] = mu;
          rq[j] = rsqrtf(var + 1e-5f);
        }
        int rowb = rbase + mt*16 + g16*4;
        #pragma unroll
        for (int nt = 0; nt < 8; ++nt){
          int col = nt*16 + l15;
          float lg = lng_s[col], lb = lnb_s[col];
          #pragma unroll
          for (int j = 0; j < 4; ++j){
            float x = (acc[mt][nt][j] - rs[j]) * rq[j] * lg + lb;
            int row = rowb + j;
            H[row*DM + (col ^ ((row & 7) << 3))] = f2b(x);
          }
        }
      }
    }

    // ---------- FFN: 16 chunks of 32 hidden, all wave-local, no barriers ----------
    {
      const unsigned short* W1b = WL + 16384;
      const unsigned short* W2b = WL + 81920;
      f32x4 c2[2][8];
      #pragma unroll
      for (int mt = 0; mt < 2; ++mt)
        #pragma unroll
        for (int nt = 0; nt < 8; ++nt){ f32x4 z; z[0]=z[1]=z[2]=z[3]=0.f; c2[mt][nt]=z; }
      #pragma unroll 1
      for (int c = 0; c < 16; ++c){
        // FFN1: Hc = relu(X @ W1c + b1c) -> Cb (stride 40, own rows)
        const bf16x8* B1 = (const bf16x8*)(W1b + c*4096);
        f32x4 hc[2][2];
        #pragma unroll
        for (int mt = 0; mt < 2; ++mt)
          #pragma unroll
          for (int nt = 0; nt < 2; ++nt){ f32x4 z; z[0]=z[1]=z[2]=z[3]=0.f; hc[mt][nt]=z; }
        #pragma unroll 1
        for (int kk = 0; kk < 4; ++kk){
          bf16x8 a0 = ldfrag128(H, rbase + l15, kk, g16);
          bf16x8 a1 = ldfrag128(H, rbase + 16 + l15, kk, g16);
          __builtin_amdgcn_s_setprio(1);
          #pragma unroll
          for (int nt = 0; nt < 2; ++nt){
            bf16x8 bb = B1[(kk*2 + nt)*64 + lane];
            hc[0][nt] = mfma16(a0, bb, hc[0][nt]);
            hc[1][nt] = mfma16(a1, bb, hc[1][nt]);
          }
          __builtin_amdgcn_s_setprio(0);
        }
        #pragma unroll
        for (int mt = 0; mt < 2; ++mt){
          int rowb = rbase + mt*16 + g16*4;
          #pragma unroll
          for (int nt = 0; nt < 2; ++nt){
            int col = nt*16 + l15;
            float bv = b1_s[c*32 + col];
            #pragma unroll
            for (int j = 0; j < 4; ++j){
              float v = fmaxf(hc[mt][nt][j] + bv, 0.f);
              Cb[(rowb + j)*CBS + col] = f2b(v);
            }
          }
        }
        // FFN2: c2 += Hc @ W2c (K=32; same-wave LDS dep via lgkmcnt)
        const bf16x8* B2 = (const bf16x8*)(W2b + c*4096);
        {
          bf16x8 a0 = *(const bf16x8*)&Cb[(rbase + l15)*CBS + g16*8];
          bf16x8 a1 = *(const bf16x8*)&Cb[(rbase + 16 + l15)*CBS + g16*8];
          __builtin_amdgcn_s_setprio(1);
          #pragma unroll
          for (int nt = 0; nt < 8; ++nt){
            bf16x8 bb = B2[nt*64 + lane];
            c2[0][nt] = mfma16(a0, bb, c2[0][nt]);
            c2[1][nt] = mfma16(a1, bb, c2[1][nt]);
          }
          __builtin_amdgcn_s_setprio(0);
        }
      }

      // ---------- Phase D: h = X + c2 + b2 -> H (in place, own rows) ----------
      #pragma unroll
      for (int mt = 0; mt < 2; ++mt){
        int rowb = rbase + mt*16 + g16*4;
        #pragma unroll
        for (int nt = 0; nt < 8; ++nt){
          int col = nt*16 + l15;
          float b2v = b2_s[col];
          #pragma unroll
          for (int j = 0; j < 4; ++j){
            int row = rowb + j;
            int p = row*DM + (col ^ ((row & 7) << 3));
            float x = b2f(H[p]);
            H[p] = f2b(x + c2[mt][nt][j] + b2v);
          }
        }
      }
    }
    __syncthreads();   // barrier 2: h visible for next layer / readout
  }

  // ---------------- readout ----------------
  {
    int gi = tid >> 4;
    int g  = tid & 15;
    if (gi < nvalid) {
      float m[8];
      #pragma unroll
      for (int i = 0; i < 8; ++i) m[i] = 0.f;
      #pragma unroll
      for (int j = 0; j < NPG; ++j){
        int row = gi*NPG + j;
        bf16x8 hv = *(const bf16x8*)&H[row*DM + ((g ^ (row & 7)) << 3)];
        #pragma unroll
        for (int i = 0; i < 8; ++i) m[i] += b2f((unsigned short)hv[i]);
      }
      const float4* fw = (const float4*)&fcw[g*8];
      float4 w0 = fw[0], w1 = fw[1];
      float dot = m[0]*w0.x + m[1]*w0.y + m[2]*w0.z + m[3]*w0.w
                + m[4]*w1.x + m[5]*w1.y + m[6]*w1.z + m[7]*w1.w;
      dot *= (1.f/9.f);
      #pragma unroll
      for (int mm = 1; mm < 16; mm <<= 1) dot += __shfl_xor(dot, mm, 64);
      if ((tid & 15) == 0){
        float z = dot + fcb[0];
        out[g0 + gi] = 1.f / (1.f + __expf(-z));
      }
    }
  }
}

extern "C" void kernel_launch(void* const* d_in, const int* in_sizes, int n_in,
                              void* d_out, int out_size, void* d_ws, size_t ws_size,
                              hipStream_t stream)
{
  const float* op_table = (const float*)d_in[0];
  const float* dev_emb  = (const float*)d_in[1];
  const float* Wg  = (const float*)d_in[2];
  const float* bg  = (const float*)d_in[3];
  const float* lng = (const float*)d_in[4];
  const float* lnb = (const float*)d_in[5];
  const float* W1  = (const float*)d_in[6];
  const float* b1  = (const float*)d_in[7];
  const float* W2  = (const float*)d_in[8];
  const float* b2  = (const float*)d_in[9];
  const float* fcw = (const float*)d_in[10];
  const float* fcb = (const float*)d_in[11];
  const int* op_idx = (const int*)d_in[12];
  const int* srcA   = (const int*)d_in[13];
  const int* dstA   = (const int*)d_in[14];
  unsigned short* wsT = (unsigned short*)d_ws;

  wtr_kernel<<<2304, 256, 0, stream>>>(Wg, W1, W2, wsT);
  gcn_kernel<<<NBLK, 256, 0, stream>>>(op_table, dev_emb, bg, lng, lnb, b1, b2,
                                       fcw, fcb, op_idx, srcA, dstA, wsT,
                                       (float*)d_out);
}

// Round 13
// 296.671 us; speedup vs baseline: 2.5793x; 1.5443x over previous
//
#include <hip/hip_runtime.h>

#define NGRAPH 16384
#define NPG    9
#define DM     128
#define NLAY   4
#define EPG    16
#define GPB    14
#define RPB    128
#define NBLK   1171   /* ceil(16384/14) */
#define CBS    40     /* Cb padded stride (elems) */
#define WPL    147456 /* weight elems per layer in wsT */

typedef __attribute__((ext_vector_type(8))) short bf16x8;
typedef __attribute__((ext_vector_type(4))) float f32x4;

__device__ __forceinline__ float b2f(unsigned short u){
  union { unsigned int i; float f; } v; v.i = ((unsigned int)u) << 16; return v.f;
}
__device__ __forceinline__ unsigned short f2b(float f){
  union { float fv; unsigned int i; } v; v.fv = f;
  unsigned int r = v.i + 0x7FFFu + ((v.i >> 16) & 1u);
  return (unsigned short)(r >> 16);
}

__device__ __forceinline__ bf16x8 ldfrag128(const unsigned short* buf, int row, int kk, int g16){
  return *(const bf16x8*)&buf[row*DM + ((kk*32 + g16*8) ^ ((row & 7) << 3))];
}
__device__ __forceinline__ f32x4 mfma16(bf16x8 a, bf16x8 b, f32x4 c){
  return __builtin_amdgcn_mfma_f32_16x16x32_bf16(a, b, c, 0, 0, 0);
}

// Weight pre-transform: f32 -> bf16, fragment-linear in wsT.
// Per layer l (base l*WPL), frag slot s of 288, each 512 bf16 (64 lanes x 8):
//  s 0..31   : GCN Wg   frag (kk=s>>3, nt=s&7)           k=kk*32+g16*8+e, n=nt*16+l15
//  s 32..159 : W1 chunk c=(s-32)>>3, fi=(s-32)&7 -> kk=fi>>1, nt=fi&1;
//              k=kk*32+g16*8+e, n=c*32+nt*16+l15
//  s 160..287: W2 chunk c=(s-160)>>3, nt=(s-160)&7; k=c*32+g16*8+e, n=nt*16+l15
__global__ void wtr_kernel(const float* __restrict__ Wg,
                           const float* __restrict__ W1,
                           const float* __restrict__ W2,
                           unsigned short* __restrict__ wsT){
  int idx = blockIdx.x * 256 + threadIdx.x;   // 2304 blocks -> 589824 = 1152*512
  int e    = idx & 7;
  int lane = (idx >> 3) & 63;
  int f    = idx >> 9;                        // 0..1151
  int l = f / 288, s = f - l*288;
  int l15 = lane & 15, g16 = lane >> 4;
  float v;
  if (s < 32){
    int kk = s >> 3, nt = s & 7;
    v = Wg[l*16384 + (kk*32 + g16*8 + e)*128 + nt*16 + l15];
  } else if (s < 160){
    int s2 = s - 32; int c = s2 >> 3, fi = s2 & 7;
    int kk = fi >> 1, nt = fi & 1;
    v = W1[l*65536 + (kk*32 + g16*8 + e)*512 + c*32 + nt*16 + l15];
  } else {
    int s3 = s - 160; int c = s3 >> 3, nt = s3 & 7;
    v = W2[l*65536 + (c*32 + g16*8 + e)*128 + nt*16 + l15];
  }
  wsT[f*512 + lane*8 + e] = f2b(v);
}

__global__ void __launch_bounds__(256, 2)
gcn_kernel(const float* __restrict__ op_table,
           const float* __restrict__ dev_emb,
           const float* __restrict__ bgp,
           const float* __restrict__ lngp,
           const float* __restrict__ lnbp,
           const float* __restrict__ b1p,
           const float* __restrict__ b2p,
           const float* __restrict__ fcw,
           const float* __restrict__ fcb,
           const int* __restrict__ op_idx,
           const int* __restrict__ srcA,
           const int* __restrict__ dstA,
           const unsigned short* __restrict__ wsT,
           float* __restrict__ out)
{
  __shared__ unsigned short H[RPB*DM];     // 32 KB: h / agg / X, swizzled stride-128
  __shared__ unsigned short Cb[RPB*CBS];   // 10 KB: Hc chunk (stride 40, wave-own rows)
  __shared__ float cntF[GPB][81];          // normalized adjacency (isd folded)
  __shared__ float isd_s[RPB];
  __shared__ float bg_s[DM], lng_s[DM], lnb_s[DM], b2_s[DM];
  __shared__ float b1_s[4*DM];

  const int tid  = threadIdx.x;
  const int w    = tid >> 6;
  const int lane = tid & 63;
  const int g16  = lane >> 4;
  const int l15  = lane & 15;
  const int rbase = w * 32;
  const int g0 = blockIdx.x * GPB;
  const int nvalid = (NGRAPH - g0 < GPB) ? (NGRAPH - g0) : GPB;

  // ---------------- preamble ----------------
  for (int i = tid; i < GPB*81; i += 256) (&cntF[0][0])[i] = 0.f;

  { // h0 = op_table[idx] + device_emb -> H swizzled; zeros for pad/invalid rows
    int r  = tid >> 1;
    int gh = (tid & 1) * 8;
    int gi = r / NPG;
    int j  = r - gi*NPG;
    if (r < GPB*NPG && gi < nvalid) {
      int idx = op_idx[(g0 + gi)*NPG + j];
      const float4* ot = (const float4*)&op_table[idx*DM + gh*8];
      const float4* de = (const float4*)&dev_emb[gh*8];
      #pragma unroll
      for (int i = 0; i < 8; ++i){
        float4 a0 = ot[2*i], a1 = ot[2*i+1];
        float4 d0 = de[2*i], d1 = de[2*i+1];
        bf16x8 o;
        o[0] = (short)f2b(a0.x + d0.x); o[1] = (short)f2b(a0.y + d0.y);
        o[2] = (short)f2b(a0.z + d0.z); o[3] = (short)f2b(a0.w + d0.w);
        o[4] = (short)f2b(a1.x + d1.x); o[5] = (short)f2b(a1.y + d1.y);
        o[6] = (short)f2b(a1.z + d1.z); o[7] = (short)f2b(a1.w + d1.w);
        int g = gh + i;
        *(bf16x8*)&H[r*DM + ((g ^ (r & 7)) << 3)] = o;
      }
    } else {
      bf16x8 z;
      #pragma unroll
      for (int q = 0; q < 8; ++q) z[q] = 0;
      #pragma unroll
      for (int i = 0; i < 8; ++i){
        int g = gh + i;
        *(bf16x8*)&H[r*DM + ((g ^ (r & 7)) << 3)] = z;
      }
    }
  }
  __syncthreads();

  if (tid < GPB && tid < nvalid) { // 9x9 count matrix incl. self loops
    float* c = cntF[tid];
    for (int e = 0; e < EPG; ++e){
      int s = srcA[(g0 + tid)*EPG + e];
      int d = dstA[(g0 + tid)*EPG + e];
      c[(s % NPG)*NPG + (d % NPG)] += 1.f;
    }
    #pragma unroll
    for (int j = 0; j < NPG; ++j) c[j*NPG + j] += 1.f;
  }
  __syncthreads();

  if (tid < RPB) { // isd = rsqrt(column sums)
    int gi = tid / NPG;
    if (tid < GPB*NPG && gi < nvalid) {
      int jd = tid - gi*NPG;
      float s = 0.f;
      #pragma unroll
      for (int js = 0; js < NPG; ++js) s += cntF[gi][js*NPG + jd];
      isd_s[tid] = rsqrtf(s);
    } else isd_s[tid] = 1.f;
  }
  __syncthreads();

  for (int idx = tid; idx < GPB*81; idx += 256){ // fold isd into cnt
    int gi = idx / 81;
    int e  = idx - gi*81;
    int js = e / 9, jd = e - js*9;
    (&cntF[0][0])[idx] *= isd_s[gi*NPG + js] * isd_s[gi*NPG + jd];
  }
  __syncthreads();

  #pragma unroll 1
  for (int l = 0; l < NLAY; ++l){
    const unsigned short* WL = wsT + l*WPL;

    // ---------- Phase A: biases + in-place agg on H (cross-wave) ----------
    if (tid < DM) {
      bg_s[tid]  = bgp [l*DM + tid];
      lng_s[tid] = lngp[l*DM + tid];
      lnb_s[tid] = lnbp[l*DM + tid];
      b2_s[tid]  = b2p [l*DM + tid];
    }
    b1_s[tid]       = b1p[l*4*DM + tid];
    b1_s[tid + 256] = b1p[l*4*DM + 256 + tid];
    {
      int gi = tid >> 4;
      int g  = tid & 15;
      if (gi < GPB) {
        float hs[NPG][8];
        #pragma unroll
        for (int j = 0; j < NPG; ++j){
          int row = gi*NPG + j;
          bf16x8 hv = *(const bf16x8*)&H[row*DM + ((g ^ (row & 7)) << 3)];
          #pragma unroll
          for (int i = 0; i < 8; ++i) hs[j][i] = b2f((unsigned short)hv[i]);
        }
        #pragma unroll
        for (int jd = 0; jd < NPG; ++jd){
          float av[8];
          #pragma unroll
          for (int i = 0; i < 8; ++i) av[i] = 0.f;
          #pragma unroll
          for (int js = 0; js < NPG; ++js){
            float cc = cntF[gi][js*NPG + jd];
            #pragma unroll
            for (int i = 0; i < 8; ++i) av[i] = fmaf(cc, hs[js][i], av[i]);
          }
          int row = gi*NPG + jd;
          bf16x8 o;
          #pragma unroll
          for (int i = 0; i < 8; ++i) o[i] = (short)f2b(av[i]);
          *(bf16x8*)&H[row*DM + ((g ^ (row & 7)) << 3)] = o;
        }
      } else { // zero pad rows 126,127
        int k2 = tid - GPB*16;
        int row = GPB*NPG + (k2 >> 4);
        int gg = k2 & 15;
        bf16x8 z;
        #pragma unroll
        for (int q = 0; q < 8; ++q) z[q] = 0;
        *(bf16x8*)&H[row*DM + ((gg ^ (row & 7)) << 3)] = z;
      }
    }
    __syncthreads();   // barrier 1: agg + biases visible

    // ---------- GCN GEMM (B from global) + ReLU + LN -> X in H (wave-local) ----------
    {
      const bf16x8* Bf = (const bf16x8*)WL;
      f32x4 acc[2][8];
      #pragma unroll
      for (int mt = 0; mt < 2; ++mt)
        #pragma unroll
        for (int nt = 0; nt < 8; ++nt){ f32x4 z; z[0]=z[1]=z[2]=z[3]=0.f; acc[mt][nt]=z; }
      #pragma unroll 2
      for (int kk = 0; kk < 4; ++kk){
        bf16x8 a0 = ldfrag128(H, rbase + l15, kk, g16);
        bf16x8 a1 = ldfrag128(H, rbase + 16 + l15, kk, g16);
        __builtin_amdgcn_s_setprio(1);
        #pragma unroll
        for (int nt = 0; nt < 8; ++nt){
          bf16x8 bb = Bf[(kk*8 + nt)*64 + lane];
          acc[0][nt] = mfma16(a0, bb, acc[0][nt]);
          acc[1][nt] = mfma16(a1, bb, acc[1][nt]);
        }
        __builtin_amdgcn_s_setprio(0);
      }
      #pragma unroll
      for (int mt = 0; mt < 2; ++mt){
        float rs[4], rq[4];
        #pragma unroll
        for (int j = 0; j < 4; ++j){ rs[j] = 0.f; rq[j] = 0.f; }
        #pragma unroll
        for (int nt = 0; nt < 8; ++nt){
          #pragma unroll
          for (int j = 0; j < 4; ++j){
            float v = acc[mt][nt][j] + bg_s[nt*16 + l15];
            v = fmaxf(v, 0.f);
            acc[mt][nt][j] = v;
            rs[j] += v; rq[j] += v*v;
          }
        }
        #pragma unroll
        for (int j = 0; j < 4; ++j){
          #pragma unroll
          for (int mm = 1; mm < 16; mm <<= 1){
            rs[j] += __shfl_xor(rs[j], mm, 64);
            rq[j] += __shfl_xor(rq[j], mm, 64);
          }
          float mu  = rs[j] * (1.f/128.f);
          float var = rq[j] * (1.f/128.f) - mu*mu;
          rs[j] = mu;
          rq[j] = rsqrtf(var + 1e-5f);
        }
        int rowb = rbase + mt*16 + g16*4;
        #pragma unroll
        for (int nt = 0; nt < 8; ++nt){
          int col = nt*16 + l15;
          float lg = lng_s[col], lb = lnb_s[col];
          #pragma unroll
          for (int j = 0; j < 4; ++j){
            float x = (acc[mt][nt][j] - rs[j]) * rq[j] * lg + lb;
            int row = rowb + j;
            H[row*DM + (col ^ ((row & 7) << 3))] = f2b(x);
          }
        }
      }
    }

    // ---------- FFN: 16 chunks of 32 hidden, wave-local, no barriers ----------
    {
      const unsigned short* W1b = WL + 16384;
      const unsigned short* W2b = WL + 81920;

      // Hoist the 8 X A-fragments into registers ONCE (reused by all 16 chunks).
      // xa[kk*2+mt] = A-frag for k-slice kk, row-tile mt. Same-wave LDS dep.
      bf16x8 xa[8];
      #pragma unroll
      for (int kk = 0; kk < 4; ++kk){
        xa[kk*2 + 0] = ldfrag128(H, rbase + l15, kk, g16);
        xa[kk*2 + 1] = ldfrag128(H, rbase + 16 + l15, kk, g16);
      }

      f32x4 c2[2][8];
      #pragma unroll
      for (int mt = 0; mt < 2; ++mt)
        #pragma unroll
        for (int nt = 0; nt < 8; ++nt){ f32x4 z; z[0]=z[1]=z[2]=z[3]=0.f; c2[mt][nt]=z; }
      #pragma unroll 1
      for (int c = 0; c < 16; ++c){
        // Issue ALL B-loads for this chunk up front (8 B1 + 8 B2) -> one
        // latency wait per chunk; B2's latency hides under FFN1 compute.
        const bf16x8* B1 = (const bf16x8*)(W1b + c*4096);
        const bf16x8* B2 = (const bf16x8*)(W2b + c*4096);
        bf16x8 b1r[8], b2r[8];
        #pragma unroll
        for (int f = 0; f < 8; ++f) b1r[f] = B1[f*64 + lane];
        #pragma unroll
        for (int f = 0; f < 8; ++f) b2r[f] = B2[f*64 + lane];

        // FFN1: Hc = relu(X @ W1c + b1c) -> Cb (stride 40, own rows)
        f32x4 hc[2][2];
        #pragma unroll
        for (int mt = 0; mt < 2; ++mt)
          #pragma unroll
          for (int nt = 0; nt < 2; ++nt){ f32x4 z; z[0]=z[1]=z[2]=z[3]=0.f; hc[mt][nt]=z; }
        __builtin_amdgcn_s_setprio(1);
        #pragma unroll
        for (int kk = 0; kk < 4; ++kk){
          #pragma unroll
          for (int nt = 0; nt < 2; ++nt){
            bf16x8 bb = b1r[kk*2 + nt];
            hc[0][nt] = mfma16(xa[kk*2 + 0], bb, hc[0][nt]);
            hc[1][nt] = mfma16(xa[kk*2 + 1], bb, hc[1][nt]);
          }
        }
        __builtin_amdgcn_s_setprio(0);
        #pragma unroll
        for (int mt = 0; mt < 2; ++mt){
          int rowb = rbase + mt*16 + g16*4;
          #pragma unroll
          for (int nt = 0; nt < 2; ++nt){
            int col = nt*16 + l15;
            float bv = b1_s[c*32 + col];
            #pragma unroll
            for (int j = 0; j < 4; ++j){
              float v = fmaxf(hc[mt][nt][j] + bv, 0.f);
              Cb[(rowb + j)*CBS + col] = f2b(v);
            }
          }
        }
        // FFN2: c2 += Hc @ W2c (K=32; same-wave LDS dep via lgkmcnt)
        {
          bf16x8 a0 = *(const bf16x8*)&Cb[(rbase + l15)*CBS + g16*8];
          bf16x8 a1 = *(const bf16x8*)&Cb[(rbase + 16 + l15)*CBS + g16*8];
          __builtin_amdgcn_s_setprio(1);
          #pragma unroll
          for (int nt = 0; nt < 8; ++nt){
            c2[0][nt] = mfma16(a0, b2r[nt], c2[0][nt]);
            c2[1][nt] = mfma16(a1, b2r[nt], c2[1][nt]);
          }
          __builtin_amdgcn_s_setprio(0);
        }
      }

      // ---------- Phase D: h = X + c2 + b2 -> H (in place, own rows) ----------
      #pragma unroll
      for (int mt = 0; mt < 2; ++mt){
        int rowb = rbase + mt*16 + g16*4;
        #pragma unroll
        for (int nt = 0; nt < 8; ++nt){
          int col = nt*16 + l15;
          float b2v = b2_s[col];
          #pragma unroll
          for (int j = 0; j < 4; ++j){
            int row = rowb + j;
            int p = row*DM + (col ^ ((row & 7) << 3));
            float x = b2f(H[p]);
            H[p] = f2b(x + c2[mt][nt][j] + b2v);
          }
        }
      }
    }
    __syncthreads();   // barrier 2: h visible for next layer / readout
  }

  // ---------------- readout ----------------
  {
    int gi = tid >> 4;
    int g  = tid & 15;
    if (gi < nvalid) {
      float m[8];
      #pragma unroll
      for (int i = 0; i < 8; ++i) m[i] = 0.f;
      #pragma unroll
      for (int j = 0; j < NPG; ++j){
        int row = gi*NPG + j;
        bf16x8 hv = *(const bf16x8*)&H[row*DM + ((g ^ (row & 7)) << 3)];
        #pragma unroll
        for (int i = 0; i < 8; ++i) m[i] += b2f((unsigned short)hv[i]);
      }
      const float4* fw = (const float4*)&fcw[g*8];
      float4 w0 = fw[0], w1 = fw[1];
      float dot = m[0]*w0.x + m[1]*w0.y + m[2]*w0.z + m[3]*w0.w
                + m[4]*w1.x + m[5]*w1.y + m[6]*w1.z + m[7]*w1.w;
      dot *= (1.f/9.f);
      #pragma unroll
      for (int mm = 1; mm < 16; mm <<= 1) dot += __shfl_xor(dot, mm, 64);
      if ((tid & 15) == 0){
        float z = dot + fcb[0];
        out[g0 + gi] = 1.f / (1.f + __expf(-z));
      }
    }
  }
}

extern "C" void kernel_launch(void* const* d_in, const int* in_sizes, int n_in,
                              void* d_out, int out_size, void* d_ws, size_t ws_size,
                              hipStream_t stream)
{
  const float* op_table = (const float*)d_in[0];
  const float* dev_emb  = (const float*)d_in[1];
  const float* Wg  = (const float*)d_in[2];
  const float* bg  = (const float*)d_in[3];
  const float* lng = (const float*)d_in[4];
  const float* lnb = (const float*)d_in[5];
  const float* W1  = (const float*)d_in[6];
  const float* b1  = (const float*)d_in[7];
  const float* W2  = (const float*)d_in[8];
  const float* b2  = (const float*)d_in[9];
  const float* fcw = (const float*)d_in[10];
  const float* fcb = (const float*)d_in[11];
  const int* op_idx = (const int*)d_in[12];
  const int* srcA   = (const int*)d_in[13];
  const int* dstA   = (const int*)d_in[14];
  unsigned short* wsT = (unsigned short*)d_ws;

  wtr_kernel<<<2304, 256, 0, stream>>>(Wg, W1, W2, wsT);
  gcn_kernel<<<NBLK, 256, 0, stream>>>(op_table, dev_emb, bg, lng, lnb, b1, b2,
                                       fcw, fcb, op_idx, srcA, dstA, wsT,
                                       (float*)d_out);
}

// Round 14
// 275.331 us; speedup vs baseline: 2.7792x; 1.0775x over previous
//
#include <hip/hip_runtime.h>

#define NGRAPH 16384
#define NPG    9
#define DM     128
#define NLAY   4
#define EPG    16
#define GPB    14
#define RPB    128
#define NBLK   1171   /* ceil(16384/14) */
#define CBS    40     /* Cb padded stride (elems) */
#define WPL    147456 /* weight elems per layer in wsT */

typedef __attribute__((ext_vector_type(8))) short bf16x8;
typedef __attribute__((ext_vector_type(4))) float f32x4;
typedef __attribute__((ext_vector_type(2))) float f32x2;
typedef __attribute__((ext_vector_type(4))) unsigned int u32x4;

__device__ __forceinline__ float b2f(unsigned short u){
  union { unsigned int i; float f; } v; v.i = ((unsigned int)u) << 16; return v.f;
}
__device__ __forceinline__ unsigned short f2b(float f){
  union { float fv; unsigned int i; } v; v.fv = f;
  unsigned int r = v.i + 0x7FFFu + ((v.i >> 16) & 1u);
  return (unsigned short)(r >> 16);
}
// HW packed f32->bf16 (RNE): dst[15:0]=bf16(lo), dst[31:16]=bf16(hi)
__device__ __forceinline__ unsigned int cvt2(float lo, float hi){
  unsigned int r;
  asm("v_cvt_pk_bf16_f32 %0, %1, %2" : "=v"(r) : "v"(lo), "v"(hi));
  return r;
}
__device__ __forceinline__ float uasf(unsigned int u){
  union { unsigned int i; float f; } v; v.i = u; return v.f;
}

__device__ __forceinline__ bf16x8 ldfrag128(const unsigned short* buf, int row, int kk, int g16){
  return *(const bf16x8*)&buf[row*DM + ((kk*32 + g16*8) ^ ((row & 7) << 3))];
}
__device__ __forceinline__ f32x4 mfma16(bf16x8 a, bf16x8 b, f32x4 c){
  return __builtin_amdgcn_mfma_f32_16x16x32_bf16(a, b, c, 0, 0, 0);
}

// Weight pre-transform: f32 -> bf16, fragment-linear in wsT.
// Per layer l (base l*WPL), frag slot s of 288, each 512 bf16 (64 lanes x 8):
//  s 0..31   : GCN Wg   frag (kk=s>>3, nt=s&7)           k=kk*32+g16*8+e, n=nt*16+l15
//  s 32..159 : W1 chunk c=(s-32)>>3, fi=(s-32)&7 -> kk=fi>>1, nt=fi&1;
//              k=kk*32+g16*8+e, n=c*32+nt*16+l15
//  s 160..287: W2 chunk c=(s-160)>>3, nt=(s-160)&7; k=c*32+g16*8+e, n=nt*16+l15
__global__ void wtr_kernel(const float* __restrict__ Wg,
                           const float* __restrict__ W1,
                           const float* __restrict__ W2,
                           unsigned short* __restrict__ wsT){
  int idx = blockIdx.x * 256 + threadIdx.x;   // 2304 blocks -> 589824 = 1152*512
  int e    = idx & 7;
  int lane = (idx >> 3) & 63;
  int f    = idx >> 9;                        // 0..1151
  int l = f / 288, s = f - l*288;
  int l15 = lane & 15, g16 = lane >> 4;
  float v;
  if (s < 32){
    int kk = s >> 3, nt = s & 7;
    v = Wg[l*16384 + (kk*32 + g16*8 + e)*128 + nt*16 + l15];
  } else if (s < 160){
    int s2 = s - 32; int c = s2 >> 3, fi = s2 & 7;
    int kk = fi >> 1, nt = fi & 1;
    v = W1[l*65536 + (kk*32 + g16*8 + e)*512 + c*32 + nt*16 + l15];
  } else {
    int s3 = s - 160; int c = s3 >> 3, nt = s3 & 7;
    v = W2[l*65536 + (c*32 + g16*8 + e)*128 + nt*16 + l15];
  }
  wsT[f*512 + lane*8 + e] = f2b(v);
}

__global__ void __launch_bounds__(256, 2)
gcn_kernel(const float* __restrict__ op_table,
           const float* __restrict__ dev_emb,
           const float* __restrict__ bgp,
           const float* __restrict__ lngp,
           const float* __restrict__ lnbp,
           const float* __restrict__ b1p,
           const float* __restrict__ b2p,
           const float* __restrict__ fcw,
           const float* __restrict__ fcb,
           const int* __restrict__ op_idx,
           const int* __restrict__ srcA,
           const int* __restrict__ dstA,
           const unsigned short* __restrict__ wsT,
           float* __restrict__ out)
{
  __shared__ unsigned short H[RPB*DM];     // 32 KB: h / agg / X, swizzled stride-128
  __shared__ unsigned short Cb[RPB*CBS];   // 10 KB: Hc chunk (stride 40, wave-own rows)
  __shared__ float cntF[GPB][81];          // normalized adjacency (isd folded)
  __shared__ float isd_s[RPB];
  __shared__ float bg_s[DM], lng_s[DM], lnb_s[DM], b2_s[DM];
  __shared__ float b1_s[4*DM];

  const int tid  = threadIdx.x;
  const int w    = tid >> 6;
  const int lane = tid & 63;
  const int g16  = lane >> 4;
  const int l15  = lane & 15;
  const int rbase = w * 32;
  const int g0 = blockIdx.x * GPB;
  const int nvalid = (NGRAPH - g0 < GPB) ? (NGRAPH - g0) : GPB;

  // ---------------- preamble ----------------
  for (int i = tid; i < GPB*81; i += 256) (&cntF[0][0])[i] = 0.f;

  { // h0 = op_table[idx] + device_emb -> H swizzled; zeros for pad/invalid rows
    int r  = tid >> 1;
    int gh = (tid & 1) * 8;
    int gi = r / NPG;
    int j  = r - gi*NPG;
    if (r < GPB*NPG && gi < nvalid) {
      int idx = op_idx[(g0 + gi)*NPG + j];
      const float4* ot = (const float4*)&op_table[idx*DM + gh*8];
      const float4* de = (const float4*)&dev_emb[gh*8];
      #pragma unroll
      for (int i = 0; i < 8; ++i){
        float4 a0 = ot[2*i], a1 = ot[2*i+1];
        float4 d0 = de[2*i], d1 = de[2*i+1];
        u32x4 o;
        o[0] = cvt2(a0.x + d0.x, a0.y + d0.y);
        o[1] = cvt2(a0.z + d0.z, a0.w + d0.w);
        o[2] = cvt2(a1.x + d1.x, a1.y + d1.y);
        o[3] = cvt2(a1.z + d1.z, a1.w + d1.w);
        int g = gh + i;
        *(u32x4*)&H[r*DM + ((g ^ (r & 7)) << 3)] = o;
      }
    } else {
      u32x4 z; z[0]=z[1]=z[2]=z[3]=0u;
      #pragma unroll
      for (int i = 0; i < 8; ++i){
        int g = gh + i;
        *(u32x4*)&H[r*DM + ((g ^ (r & 7)) << 3)] = z;
      }
    }
  }
  __syncthreads();

  if (tid < GPB && tid < nvalid) { // 9x9 count matrix incl. self loops
    float* c = cntF[tid];
    for (int e = 0; e < EPG; ++e){
      int s = srcA[(g0 + tid)*EPG + e];
      int d = dstA[(g0 + tid)*EPG + e];
      c[(s % NPG)*NPG + (d % NPG)] += 1.f;
    }
    #pragma unroll
    for (int j = 0; j < NPG; ++j) c[j*NPG + j] += 1.f;
  }
  __syncthreads();

  if (tid < RPB) { // isd = rsqrt(column sums)
    int gi = tid / NPG;
    if (tid < GPB*NPG && gi < nvalid) {
      int jd = tid - gi*NPG;
      float s = 0.f;
      #pragma unroll
      for (int js = 0; js < NPG; ++js) s += cntF[gi][js*NPG + jd];
      isd_s[tid] = rsqrtf(s);
    } else isd_s[tid] = 1.f;
  }
  __syncthreads();

  for (int idx = tid; idx < GPB*81; idx += 256){ // fold isd into cnt
    int gi = idx / 81;
    int e  = idx - gi*81;
    int js = e / 9, jd = e - js*9;
    (&cntF[0][0])[idx] *= isd_s[gi*NPG + js] * isd_s[gi*NPG + jd];
  }
  __syncthreads();

  #pragma unroll 1
  for (int l = 0; l < NLAY; ++l){
    const unsigned short* WL = wsT + l*WPL;

    // ---------- Phase A: biases + in-place agg on H (cross-wave) ----------
    if (tid < DM) {
      bg_s[tid]  = bgp [l*DM + tid];
      lng_s[tid] = lngp[l*DM + tid];
      lnb_s[tid] = lnbp[l*DM + tid];
      b2_s[tid]  = b2p [l*DM + tid];
    }
    b1_s[tid]       = b1p[l*4*DM + tid];
    b1_s[tid + 256] = b1p[l*4*DM + 256 + tid];
    {
      int gi = tid >> 4;
      int g  = tid & 15;
      if (gi < GPB) {
        f32x2 hs[NPG][4];
        #pragma unroll
        for (int j = 0; j < NPG; ++j){
          int row = gi*NPG + j;
          u32x4 hv = *(const u32x4*)&H[row*DM + ((g ^ (row & 7)) << 3)];
          #pragma unroll
          for (int i = 0; i < 4; ++i){
            f32x2 t;
            t[0] = uasf(hv[i] << 16);
            t[1] = uasf(hv[i] & 0xffff0000u);
            hs[j][i] = t;
          }
        }
        #pragma unroll
        for (int jd = 0; jd < NPG; ++jd){
          f32x2 av[4];
          #pragma unroll
          for (int i = 0; i < 4; ++i){ f32x2 z; z[0]=0.f; z[1]=0.f; av[i]=z; }
          #pragma unroll
          for (int js = 0; js < NPG; ++js){
            float c = cntF[gi][js*NPG + jd];
            f32x2 cc; cc[0]=c; cc[1]=c;
            #pragma unroll
            for (int i = 0; i < 4; ++i)
              av[i] = __builtin_elementwise_fma(cc, hs[js][i], av[i]);
          }
          int row = gi*NPG + jd;
          u32x4 o;
          #pragma unroll
          for (int i = 0; i < 4; ++i) o[i] = cvt2(av[i][0], av[i][1]);
          *(u32x4*)&H[row*DM + ((g ^ (row & 7)) << 3)] = o;
        }
      } else { // zero pad rows 126,127
        int k2 = tid - GPB*16;
        int row = GPB*NPG + (k2 >> 4);
        int gg = k2 & 15;
        u32x4 z; z[0]=z[1]=z[2]=z[3]=0u;
        *(u32x4*)&H[row*DM + ((gg ^ (row & 7)) << 3)] = z;
      }
    }
    __syncthreads();   // barrier 1: agg + biases visible

    // ---------- GCN GEMM (B from global) + ReLU + LN -> X in H (wave-local) ----------
    {
      const bf16x8* Bf = (const bf16x8*)WL;
      f32x4 acc[2][8];
      #pragma unroll
      for (int mt = 0; mt < 2; ++mt)
        #pragma unroll
        for (int nt = 0; nt < 8; ++nt){ f32x4 z; z[0]=z[1]=z[2]=z[3]=0.f; acc[mt][nt]=z; }
      #pragma unroll 2
      for (int kk = 0; kk < 4; ++kk){
        bf16x8 a0 = ldfrag128(H, rbase + l15, kk, g16);
        bf16x8 a1 = ldfrag128(H, rbase + 16 + l15, kk, g16);
        __builtin_amdgcn_s_setprio(1);
        #pragma unroll
        for (int nt = 0; nt < 8; ++nt){
          bf16x8 bb = Bf[(kk*8 + nt)*64 + lane];
          acc[0][nt] = mfma16(a0, bb, acc[0][nt]);
          acc[1][nt] = mfma16(a1, bb, acc[1][nt]);
        }
        __builtin_amdgcn_s_setprio(0);
      }
      #pragma unroll
      for (int mt = 0; mt < 2; ++mt){
        float rs[4], rq[4];
        #pragma unroll
        for (int j = 0; j < 4; ++j){ rs[j] = 0.f; rq[j] = 0.f; }
        #pragma unroll
        for (int nt = 0; nt < 8; ++nt){
          #pragma unroll
          for (int j = 0; j < 4; ++j){
            float v = acc[mt][nt][j] + bg_s[nt*16 + l15];
            v = fmaxf(v, 0.f);
            acc[mt][nt][j] = v;
            rs[j] += v; rq[j] += v*v;
          }
        }
        #pragma unroll
        for (int j = 0; j < 4; ++j){
          #pragma unroll
          for (int mm = 1; mm < 16; mm <<= 1){
            rs[j] += __shfl_xor(rs[j], mm, 64);
            rq[j] += __shfl_xor(rq[j], mm, 64);
          }
          float mu  = rs[j] * (1.f/128.f);
          float var = rq[j] * (1.f/128.f) - mu*mu;
          rs[j] = mu;
          rq[j] = rsqrtf(var + 1e-5f);
        }
        int rowb = rbase + mt*16 + g16*4;
        #pragma unroll
        for (int nt = 0; nt < 8; ++nt){
          int col = nt*16 + l15;
          float lg = lng_s[col], lb = lnb_s[col];
          float x0 = (acc[mt][nt][0] - rs[0]) * rq[0] * lg + lb;
          float x1 = (acc[mt][nt][1] - rs[1]) * rq[1] * lg + lb;
          float x2 = (acc[mt][nt][2] - rs[2]) * rq[2] * lg + lb;
          float x3 = (acc[mt][nt][3] - rs[3]) * rq[3] * lg + lb;
          unsigned int p01 = cvt2(x0, x1);
          unsigned int p23 = cvt2(x2, x3);
          int r0 = rowb, r1 = rowb+1, r2 = rowb+2, r3 = rowb+3;
          H[r0*DM + (col ^ ((r0 & 7) << 3))] = (unsigned short)p01;
          H[r1*DM + (col ^ ((r1 & 7) << 3))] = (unsigned short)(p01 >> 16);
          H[r2*DM + (col ^ ((r2 & 7) << 3))] = (unsigned short)p23;
          H[r3*DM + (col ^ ((r3 & 7) << 3))] = (unsigned short)(p23 >> 16);
        }
      }
    }

    // ---------- FFN: 16 chunks of 32 hidden, wave-local, no barriers ----------
    {
      const unsigned short* W1b = WL + 16384;
      const unsigned short* W2b = WL + 81920;

      // Hoist the 8 X A-fragments into registers ONCE (reused by all 16 chunks).
      bf16x8 xa[8];
      #pragma unroll
      for (int kk = 0; kk < 4; ++kk){
        xa[kk*2 + 0] = ldfrag128(H, rbase + l15, kk, g16);
        xa[kk*2 + 1] = ldfrag128(H, rbase + 16 + l15, kk, g16);
      }

      f32x4 c2[2][8];
      #pragma unroll
      for (int mt = 0; mt < 2; ++mt)
        #pragma unroll
        for (int nt = 0; nt < 8; ++nt){ f32x4 z; z[0]=z[1]=z[2]=z[3]=0.f; c2[mt][nt]=z; }
      #pragma unroll 1
      for (int c = 0; c < 16; ++c){
        // Issue ALL B-loads for this chunk up front (8 B1 + 8 B2)
        const bf16x8* B1 = (const bf16x8*)(W1b + c*4096);
        const bf16x8* B2 = (const bf16x8*)(W2b + c*4096);
        bf16x8 b1r[8], b2r[8];
        #pragma unroll
        for (int f = 0; f < 8; ++f) b1r[f] = B1[f*64 + lane];
        #pragma unroll
        for (int f = 0; f < 8; ++f) b2r[f] = B2[f*64 + lane];

        // FFN1: Hc = relu(X @ W1c + b1c) -> Cb (stride 40, own rows)
        f32x4 hc[2][2];
        #pragma unroll
        for (int mt = 0; mt < 2; ++mt)
          #pragma unroll
          for (int nt = 0; nt < 2; ++nt){ f32x4 z; z[0]=z[1]=z[2]=z[3]=0.f; hc[mt][nt]=z; }
        __builtin_amdgcn_s_setprio(1);
        #pragma unroll
        for (int kk = 0; kk < 4; ++kk){
          #pragma unroll
          for (int nt = 0; nt < 2; ++nt){
            bf16x8 bb = b1r[kk*2 + nt];
            hc[0][nt] = mfma16(xa[kk*2 + 0], bb, hc[0][nt]);
            hc[1][nt] = mfma16(xa[kk*2 + 1], bb, hc[1][nt]);
          }
        }
        __builtin_amdgcn_s_setprio(0);
        #pragma unroll
        for (int mt = 0; mt < 2; ++mt){
          int rowb = rbase + mt*16 + g16*4;
          #pragma unroll
          for (int nt = 0; nt < 2; ++nt){
            int col = nt*16 + l15;
            float bv = b1_s[c*32 + col];
            float v0 = fmaxf(hc[mt][nt][0] + bv, 0.f);
            float v1 = fmaxf(hc[mt][nt][1] + bv, 0.f);
            float v2 = fmaxf(hc[mt][nt][2] + bv, 0.f);
            float v3 = fmaxf(hc[mt][nt][3] + bv, 0.f);
            unsigned int p01 = cvt2(v0, v1);
            unsigned int p23 = cvt2(v2, v3);
            Cb[(rowb + 0)*CBS + col] = (unsigned short)p01;
            Cb[(rowb + 1)*CBS + col] = (unsigned short)(p01 >> 16);
            Cb[(rowb + 2)*CBS + col] = (unsigned short)p23;
            Cb[(rowb + 3)*CBS + col] = (unsigned short)(p23 >> 16);
          }
        }
        // FFN2: c2 += Hc @ W2c (K=32; same-wave LDS dep via lgkmcnt)
        {
          bf16x8 a0 = *(const bf16x8*)&Cb[(rbase + l15)*CBS + g16*8];
          bf16x8 a1 = *(const bf16x8*)&Cb[(rbase + 16 + l15)*CBS + g16*8];
          __builtin_amdgcn_s_setprio(1);
          #pragma unroll
          for (int nt = 0; nt < 8; ++nt){
            c2[0][nt] = mfma16(a0, b2r[nt], c2[0][nt]);
            c2[1][nt] = mfma16(a1, b2r[nt], c2[1][nt]);
          }
          __builtin_amdgcn_s_setprio(0);
        }
      }

      // ---------- Phase D: h = X + c2 + b2 -> H (in place, own rows) ----------
      #pragma unroll
      for (int mt = 0; mt < 2; ++mt){
        int rowb = rbase + mt*16 + g16*4;
        #pragma unroll
        for (int nt = 0; nt < 8; ++nt){
          int col = nt*16 + l15;
          float b2v = b2_s[col];
          int p0 = (rowb+0)*DM + (col ^ (((rowb+0) & 7) << 3));
          int p1 = (rowb+1)*DM + (col ^ (((rowb+1) & 7) << 3));
          int p2 = (rowb+2)*DM + (col ^ (((rowb+2) & 7) << 3));
          int p3 = (rowb+3)*DM + (col ^ (((rowb+3) & 7) << 3));
          float s0 = b2f(H[p0]) + c2[mt][nt][0] + b2v;
          float s1 = b2f(H[p1]) + c2[mt][nt][1] + b2v;
          float s2 = b2f(H[p2]) + c2[mt][nt][2] + b2v;
          float s3 = b2f(H[p3]) + c2[mt][nt][3] + b2v;
          unsigned int p01 = cvt2(s0, s1);
          unsigned int p23 = cvt2(s2, s3);
          H[p0] = (unsigned short)p01;
          H[p1] = (unsigned short)(p01 >> 16);
          H[p2] = (unsigned short)p23;
          H[p3] = (unsigned short)(p23 >> 16);
        }
      }
    }
    __syncthreads();   // barrier 2: h visible for next layer / readout
  }

  // ---------------- readout ----------------
  {
    int gi = tid >> 4;
    int g  = tid & 15;
    if (gi < nvalid) {
      float m[8];
      #pragma unroll
      for (int i = 0; i < 8; ++i) m[i] = 0.f;
      #pragma unroll
      for (int j = 0; j < NPG; ++j){
        int row = gi*NPG + j;
        bf16x8 hv = *(const bf16x8*)&H[row*DM + ((g ^ (row & 7)) << 3)];
        #pragma unroll
        for (int i = 0; i < 8; ++i) m[i] += b2f((unsigned short)hv[i]);
      }
      const float4* fw = (const float4*)&fcw[g*8];
      float4 w0 = fw[0], w1 = fw[1];
      float dot = m[0]*w0.x + m[1]*w0.y + m[2]*w0.z + m[3]*w0.w
                + m[4]*w1.x + m[5]*w1.y + m[6]*w1.z + m[7]*w1.w;
      dot *= (1.f/9.f);
      #pragma unroll
      for (int mm = 1; mm < 16; mm <<= 1) dot += __shfl_xor(dot, mm, 64);
      if ((tid & 15) == 0){
        float z = dot + fcb[0];
        out[g0 + gi] = 1.f / (1.f + __expf(-z));
      }
    }
  }
}

extern "C" void kernel_launch(void* const* d_in, const int* in_sizes, int n_in,
                              void* d_out, int out_size, void* d_ws, size_t ws_size,
                              hipStream_t stream)
{
  const float* op_table = (const float*)d_in[0];
  const float* dev_emb  = (const float*)d_in[1];
  const float* Wg  = (const float*)d_in[2];
  const float* bg  = (const float*)d_in[3];
  const float* lng = (const float*)d_in[4];
  const float* lnb = (const float*)d_in[5];
  const float* W1  = (const float*)d_in[6];
  const float* b1  = (const float*)d_in[7];
  const float* W2  = (const float*)d_in[8];
  const float* b2  = (const float*)d_in[9];
  const float* fcw = (const float*)d_in[10];
  const float* fcb = (const float*)d_in[11];
  const int* op_idx = (const int*)d_in[12];
  const int* srcA   = (const int*)d_in[13];
  const int* dstA   = (const int*)d_in[14];
  unsigned short* wsT = (unsigned short*)d_ws;

  wtr_kernel<<<2304, 256, 0, stream>>>(Wg, W1, W2, wsT);
  gcn_kernel<<<NBLK, 256, 0, stream>>>(op_table, dev_emb, bg, lng, lnb, b1, b2,
                                       fcw, fcb, op_idx, srcA, dstA, wsT,
                                       (float*)d_out);
}